// Round 1
// baseline (1045.821 us; speedup 1.0000x reference)
//
#include <hip/hip_runtime.h>

#define DZ 64
#define DX 32
#define DS 16
#define TT 1024
#define NS 1024
#define PF 8   // prefetch depth (steps)

__device__ __forceinline__ float softplus_eps(float x) {
    // jax.nn.softplus = max(x,0) + log1p(exp(-|x|)); +1e-6
    return fmaxf(x, 0.f) + log1pf(expf(-fabsf(x))) + 1e-6f;
}

__global__ __launch_bounds__(256, 1) void plrnn_kernel(
    const float* __restrict__ u,   // (T, N, 16)
    const float* __restrict__ z0,  // (N, 64)
    const float* __restrict__ nz,  // (T, N, 64)
    const float* __restrict__ nx,  // (T, N, 32)
    const float* __restrict__ AW,  // (64, 64)
    const float* __restrict__ Cm,  // (64, 16)
    const float* __restrict__ Bm,  // (32, 64)
    const float* __restrict__ Q,   // (64,)
    const float* __restrict__ R,   // (32,)
    float* __restrict__ zo,        // (T, N, 64)
    float* __restrict__ xo)        // (T, N, 32)
{
    const int lane = threadIdx.x & 63;
    const int wv   = threadIdx.x >> 6;          // wave id in block (0..3)
    const int sim  = (blockIdx.x << 2) | wv;    // one wave per sim

    // Wave-private LDS slices: no __syncthreads needed; intra-wave
    // ds_write -> ds_read ordering is enforced by lgkmcnt (aliasing).
    __shared__ float ldsr[4][DZ];  // raw z broadcast
    __shared__ float ldsa[4][DZ];  // relu(z) broadcast
    __shared__ float ldsu[4][DS];  // u_t broadcast

    // ---- persistent per-lane weights ----
    float Wrow[DZ];                       // W_off[lane][k] (diag zeroed)
    #pragma unroll
    for (int k = 0; k < DZ; ++k) {
        float w = AW[lane * DZ + k];
        Wrow[k] = (k == lane) ? 0.f : w;  // compile-time k, runtime select
    }
    const float Ad = AW[lane * DZ + lane];
    float Crow[DS];
    #pragma unroll
    for (int s = 0; s < DS; ++s) Crow[s] = Cm[lane * DS + s];

    const int xrow  = lane & 31;          // x output row this lane serves
    const int kbase = (lane >> 5) << 5;   // 0 (low half) or 32 (high half)
    float Brow[32];                       // B[xrow][kbase + 0..31]
    #pragma unroll
    for (int k = 0; k < 32; ++k) Brow[k] = Bm[xrow * DZ + kbase + k];

    const float qv = softplus_eps(Q[lane]);
    const float rv = softplus_eps(R[xrow]);

    float zl = z0[(size_t)sim * DZ + lane];   // z_t[lane]

    const float* pnz = nz + (size_t)sim * DZ + lane;
    const float* pnx = nx + (size_t)sim * DX + xrow;
    const float* pu  = u  + (size_t)sim * DS + (lane & 15);
    float* pz = zo + (size_t)sim * DZ + lane;
    float* px = xo + (size_t)sim * DX + xrow;

    const size_t snz = (size_t)NS * DZ;   // per-step strides
    const size_t snx = (size_t)NS * DX;
    const size_t su  = (size_t)NS * DS;

    // ---- depth-PF register prefetch ----
    float nzb[PF], nxb[PF], ub[PF];
    #pragma unroll
    for (int j = 0; j < PF; ++j) {
        nzb[j] = pnz[(size_t)j * snz];
        nxb[j] = (lane < DX) ? pnx[(size_t)j * snx] : 0.f;
        ub[j]  = (lane < DS) ? pu[(size_t)j * su] : 0.f;
    }

    for (int t0 = 0; t0 < TT; t0 += PF) {
        #pragma unroll
        for (int j = 0; j < PF; ++j) {
            const int t = t0 + j;
            const float vnz = nzb[j];
            const float vnx = nxb[j];
            const float vu  = ub[j];
            // issue prefetch for step t+PF (independent -> schedules early)
            if (t + PF < TT) {
                nzb[j] = pnz[(size_t)(t + PF) * snz];
                nxb[j] = (lane < DX) ? pnx[(size_t)(t + PF) * snx] : 0.f;
                ub[j]  = (lane < DS) ? pu[(size_t)(t + PF) * su] : 0.f;
            }

            // emit z_t (scan outputs carry BEFORE update; z[0] == z0)
            pz[(size_t)t * snz] = zl;

            // broadcast z_t through wave-private LDS
            ldsr[wv][lane] = zl;
            ldsa[wv][lane] = fmaxf(zl, 0.f);
            if (lane < DS) ldsu[wv][lane] = vu;

            // ---- x_t = z_t @ B.T + nx*r ; k-sum split across lane halves
            float xa0 = 0.f, xa1 = 0.f, xa2 = 0.f, xa3 = 0.f;
            #pragma unroll
            for (int k = 0; k < 32; k += 4) {
                const float4 zz = *(const float4*)&ldsr[wv][kbase + k];
                xa0 = fmaf(Brow[k + 0], zz.x, xa0);
                xa1 = fmaf(Brow[k + 1], zz.y, xa1);
                xa2 = fmaf(Brow[k + 2], zz.z, xa2);
                xa3 = fmaf(Brow[k + 3], zz.w, xa3);
            }
            float pxs = (xa0 + xa1) + (xa2 + xa3);
            float ox = pxs + __shfl_xor(pxs, 32);   // combine halves
            ox = fmaf(vnx, rv, ox);
            if (lane < DX) px[(size_t)t * snx] = ox;

            // ---- mu = A_diag*z + relu(z) @ W_off.T + u @ C.T
            float m0 = Ad * zl, m1 = 0.f, m2 = 0.f, m3 = 0.f;
            #pragma unroll
            for (int s = 0; s < DS; s += 4) {
                const float4 uu = *(const float4*)&ldsu[wv][s];
                m0 = fmaf(Crow[s + 0], uu.x, m0);
                m1 = fmaf(Crow[s + 1], uu.y, m1);
                m2 = fmaf(Crow[s + 2], uu.z, m2);
                m3 = fmaf(Crow[s + 3], uu.w, m3);
            }
            #pragma unroll
            for (int k = 0; k < DZ; k += 4) {
                const float4 zz = *(const float4*)&ldsa[wv][k];
                m0 = fmaf(Wrow[k + 0], zz.x, m0);
                m1 = fmaf(Wrow[k + 1], zz.y, m1);
                m2 = fmaf(Wrow[k + 2], zz.z, m2);
                m3 = fmaf(Wrow[k + 3], zz.w, m3);
            }
            // z_{t+1} = mu + nz*q
            zl = fmaf(vnz, qv, (m0 + m1) + (m2 + m3));
        }
    }
}

extern "C" void kernel_launch(void* const* d_in, const int* in_sizes, int n_in,
                              void* d_out, int out_size, void* d_ws, size_t ws_size,
                              hipStream_t stream) {
    const float* u_  = (const float*)d_in[0];
    const float* z0_ = (const float*)d_in[1];
    const float* nz_ = (const float*)d_in[2];
    const float* nx_ = (const float*)d_in[3];
    const float* AW_ = (const float*)d_in[4];
    const float* C_  = (const float*)d_in[5];
    const float* B_  = (const float*)d_in[6];
    const float* Q_  = (const float*)d_in[7];
    const float* R_  = (const float*)d_in[8];

    float* zo = (float*)d_out;                        // (T,N,64) first
    float* xo = zo + (size_t)TT * NS * DZ;            // then (T,N,32)

    hipLaunchKernelGGL(plrnn_kernel, dim3(NS / 4), dim3(256), 0, stream,
                       u_, z0_, nz_, nx_, AW_, C_, B_, Q_, R_, zo, xo);
}